// Round 2
// baseline (2396.225 us; speedup 1.0000x reference)
//
#include <hip/hip_runtime.h>
#include <hip/hip_bf16.h>
#include <cstring>

// Problem constants (match reference)
#define NNODE_DIN 128
#define NNODE_DOUT 128
#define DEG 48
#define TOPK 32

typedef __bf16 bf16x8 __attribute__((ext_vector_type(8)));
typedef float floatx4 __attribute__((ext_vector_type(4)));

__device__ inline unsigned short f2bf(float f) {
    __bf16 h = (__bf16)f;
    return __builtin_bit_cast(unsigned short, h);
}
__device__ inline float bf2f(unsigned short u) {
    unsigned v = ((unsigned)u) << 16;
    return __builtin_bit_cast(float, v);
}

// ---------------------------------------------------------------------------
// Kernel 1: x = feat @ weight (fp32 accumulate). Store split-bf16: hi = bf16(x),
// lo = bf16(x - hi). Together ~2^-18 relative precision.
// Block = 256 threads; each thread: 4 rows x 16 cols. 128 rows/block.
// Weight (128x128 fp32 = 64KB) staged in LDS.
// ---------------------------------------------------------------------------
__global__ __launch_bounds__(256) void k1_gemm(
    const float* __restrict__ feat, const float* __restrict__ weight,
    unsigned short* __restrict__ xh, unsigned short* __restrict__ xl, int n) {
    __shared__ float s_wt[128 * 128];

    int t = threadIdx.x;
    const float4* wg4 = (const float4*)weight;
    float4* sw4 = (float4*)s_wt;
#pragma unroll
    for (int ii = 0; ii < 16; ++ii) sw4[ii * 256 + t] = wg4[ii * 256 + t];
    __syncthreads();

    int colgrp = t & 7;
    int rowgrp = t >> 3;
    int c0 = colgrp * 16;
    int r0 = blockIdx.x * 128 + rowgrp * 4;

    float acc[4][16];
#pragma unroll
    for (int j = 0; j < 4; ++j)
#pragma unroll
        for (int cidx = 0; cidx < 16; ++cidx) acc[j][cidx] = 0.0f;

    for (int d0 = 0; d0 < 128; d0 += 4) {
        float4 f[4];
#pragma unroll
        for (int j = 0; j < 4; ++j) {
            int r = r0 + j;
            if (r < n) {
                f[j] = *(const float4*)(feat + (size_t)r * 128 + d0);
            } else {
                f[j] = make_float4(0.f, 0.f, 0.f, 0.f);
            }
        }
#pragma unroll
        for (int i = 0; i < 4; ++i) {
#pragma unroll
            for (int cc = 0; cc < 4; ++cc) {
                int cb = (cc + colgrp) & 3;  // stagger to break LDS bank conflicts
                float4 wv = *(const float4*)&s_wt[(d0 + i) * 128 + c0 + cb * 4];
#pragma unroll
                for (int j = 0; j < 4; ++j) {
                    float fv = (&f[j].x)[i];
                    acc[j][cb * 4 + 0] = fmaf(fv, wv.x, acc[j][cb * 4 + 0]);
                    acc[j][cb * 4 + 1] = fmaf(fv, wv.y, acc[j][cb * 4 + 1]);
                    acc[j][cb * 4 + 2] = fmaf(fv, wv.z, acc[j][cb * 4 + 2]);
                    acc[j][cb * 4 + 3] = fmaf(fv, wv.w, acc[j][cb * 4 + 3]);
                }
            }
        }
    }

#pragma unroll
    for (int j = 0; j < 4; ++j) {
        int r = r0 + j;
        if (r < n) {
            unsigned uh[8], ul[8];
#pragma unroll
            for (int p = 0; p < 8; ++p) {
                float a0 = acc[j][2 * p];
                float a1 = acc[j][2 * p + 1];
                unsigned short h0 = f2bf(a0);
                unsigned short h1 = f2bf(a1);
                unsigned short l0 = f2bf(a0 - bf2f(h0));
                unsigned short l1 = f2bf(a1 - bf2f(h1));
                uh[p] = (unsigned)h0 | ((unsigned)h1 << 16);
                ul[p] = (unsigned)l0 | ((unsigned)l1 << 16);
            }
            uint4* dsth = (uint4*)(xh + (size_t)r * 128 + c0);
            dsth[0] = make_uint4(uh[0], uh[1], uh[2], uh[3]);
            dsth[1] = make_uint4(uh[4], uh[5], uh[6], uh[7]);
            uint4* dstl = (uint4*)(xl + (size_t)r * 128 + c0);
            dstl[0] = make_uint4(ul[0], ul[1], ul[2], ul[3]);
            dstl[1] = make_uint4(ul[4], ul[5], ul[6], ul[7]);
        }
    }
}

// ---------------------------------------------------------------------------
// Kernel 2: one wave (64 threads) per node.
//  A) load 49 candidate weights/ids  B) exact top-32 by (value desc, idx asc)
//  C) gather 32 x-rows (split bf16 hi/lo) into LDS
//  D) 32x32 Gram via split MFMA: G = HH^T + HL^T + LH^T (48 MFMAs)
//  E) weighted-medoid distances  F) softmax * tw / sum  G) aggregate + bias
// ---------------------------------------------------------------------------
__global__ __launch_bounds__(64) void k2_conv(
    const float* __restrict__ ew, const int* __restrict__ nbr,
    const float* __restrict__ bias, const unsigned short* __restrict__ xh,
    const unsigned short* __restrict__ xl, float* __restrict__ outp, int n) {
    __shared__ float s_w[52];
    __shared__ int s_nb[52];
    __shared__ float s_tw[32];
    __shared__ int s_id[32];
    __shared__ unsigned short s_xh[32 * 136];  // 32 rows x 128 bf16, pad to 136
    __shared__ unsigned short s_xl[32 * 136];
    __shared__ float s_diag[32];
    __shared__ float s_dist[32];
    __shared__ float s_omega[32];

    int i = blockIdx.x;
    int l = threadIdx.x;

    // A: candidates = 48 neighbors + self loop (weight 1.0)
    if (l < DEG) {
        s_w[l] = ew[(size_t)i * DEG + l];
        s_nb[l] = nbr[(size_t)i * DEG + l];
    }
    if (l == DEG) {
        s_w[DEG] = 1.0f;
        s_nb[DEG] = i;
    }
    __syncthreads();

    // B: rank-based top-k (exact jax.lax.top_k tie semantics); rank == slot
    if (l < DEG + 1) {
        float wj = s_w[l];
        int rank = 0;
        for (int t2 = 0; t2 < DEG + 1; ++t2) {
            float wt = s_w[t2];
            rank += (wt > wj) || ((wt == wj) && (t2 < l)) ? 1 : 0;
        }
        if (rank < TOPK) {
            s_tw[rank] = wj;
            s_id[rank] = s_nb[l];
        }
    }
    __syncthreads();

    // C: gather 32 rows (hi+lo, 256B each) into LDS; 4 rows per iteration
    {
        int chunk = l & 15;   // 16B chunk within row
        int ksub = l >> 4;    // which of 4 rows this iteration
#pragma unroll
        for (int it = 0; it < 8; ++it) {
            int k = it * 4 + ksub;
            size_t base = (size_t)s_id[k] * 128;
            const uint4* srch = (const uint4*)(xh + base) + chunk;
            const uint4* srcl = (const uint4*)(xl + base) + chunk;
            *(uint4*)(&s_xh[k * 136 + chunk * 8]) = *srch;
            *(uint4*)(&s_xl[k * 136 + chunk * 8]) = *srcl;
        }
    }
    __syncthreads();

    // D: Gram = X*X^T with X ~= H + L:  G = HH^T + HL^T + LH^T (LL^T ~2^-18, dropped)
    int m = l & 15;
    int q = l >> 4;
    floatx4 acc[2][2];
#pragma unroll
    for (int a = 0; a < 2; ++a)
#pragma unroll
        for (int b = 0; b < 2; ++b) acc[a][b] = (floatx4){0.f, 0.f, 0.f, 0.f};

    const __bf16* xbh = (const __bf16*)s_xh;
    const __bf16* xbl = (const __bf16*)s_xl;
#pragma unroll
    for (int kt = 0; kt < 4; ++kt) {
        bf16x8 h0 = *(const bf16x8*)(xbh + m * 136 + kt * 32 + q * 8);
        bf16x8 h1 = *(const bf16x8*)(xbh + (16 + m) * 136 + kt * 32 + q * 8);
        bf16x8 l0 = *(const bf16x8*)(xbl + m * 136 + kt * 32 + q * 8);
        bf16x8 l1 = *(const bf16x8*)(xbl + (16 + m) * 136 + kt * 32 + q * 8);
        acc[0][0] = __builtin_amdgcn_mfma_f32_16x16x32_bf16(h0, h0, acc[0][0], 0, 0, 0);
        acc[0][0] = __builtin_amdgcn_mfma_f32_16x16x32_bf16(h0, l0, acc[0][0], 0, 0, 0);
        acc[0][0] = __builtin_amdgcn_mfma_f32_16x16x32_bf16(l0, h0, acc[0][0], 0, 0, 0);
        acc[0][1] = __builtin_amdgcn_mfma_f32_16x16x32_bf16(h0, h1, acc[0][1], 0, 0, 0);
        acc[0][1] = __builtin_amdgcn_mfma_f32_16x16x32_bf16(h0, l1, acc[0][1], 0, 0, 0);
        acc[0][1] = __builtin_amdgcn_mfma_f32_16x16x32_bf16(l0, h1, acc[0][1], 0, 0, 0);
        acc[1][0] = __builtin_amdgcn_mfma_f32_16x16x32_bf16(h1, h0, acc[1][0], 0, 0, 0);
        acc[1][0] = __builtin_amdgcn_mfma_f32_16x16x32_bf16(h1, l0, acc[1][0], 0, 0, 0);
        acc[1][0] = __builtin_amdgcn_mfma_f32_16x16x32_bf16(l1, h0, acc[1][0], 0, 0, 0);
        acc[1][1] = __builtin_amdgcn_mfma_f32_16x16x32_bf16(h1, h1, acc[1][1], 0, 0, 0);
        acc[1][1] = __builtin_amdgcn_mfma_f32_16x16x32_bf16(h1, l1, acc[1][1], 0, 0, 0);
        acc[1][1] = __builtin_amdgcn_mfma_f32_16x16x32_bf16(l1, h1, acc[1][1], 0, 0, 0);
    }

    // D2: extract diagonal (sq) from Gram so that d2_aa == 0 exactly
    if (q == (m >> 2)) {
        int rd = m & 3;
        s_diag[m] = acc[0][0][rd];
        s_diag[16 + m] = acc[1][1][rd];
    }
    __syncthreads();

    // E: dist[a] = sum_b tw[b] * sqrt(d2 masked by d2>0)
#pragma unroll
    for (int ma = 0; ma < 2; ++ma) {
#pragma unroll
        for (int r = 0; r < 4; ++r) {
            int a = ma * 16 + q * 4 + r;
            float da = s_diag[a];
            float g0 = acc[ma][0][r];
            float g1 = acc[ma][1][r];
            int b0 = m;
            int b1 = 16 + m;
            float d20 = da + s_diag[b0] - 2.0f * g0;
            float d21 = da + s_diag[b1] - 2.0f * g1;
            float t0 = (d20 > 0.0f) ? sqrtf(d20) : 0.0f;
            float t1 = (d21 > 0.0f) ? sqrtf(d21) : 0.0f;
            float v = s_tw[b0] * t0 + s_tw[b1] * t1;
            v += __shfl_xor(v, 1);
            v += __shfl_xor(v, 2);
            v += __shfl_xor(v, 4);
            v += __shfl_xor(v, 8);
            if (m == 0) s_dist[a] = v;
        }
    }
    __syncthreads();

    // F: omega = exp(-dist - max(-dist)) * tw, normalized
    {
        int k32 = l & 31;
        float s = s_dist[k32];
        float mn = s;
        mn = fminf(mn, __shfl_xor(mn, 1));
        mn = fminf(mn, __shfl_xor(mn, 2));
        mn = fminf(mn, __shfl_xor(mn, 4));
        mn = fminf(mn, __shfl_xor(mn, 8));
        mn = fminf(mn, __shfl_xor(mn, 16));
        float e = expf(mn - s) * s_tw[k32];
        float sum = e;
        sum += __shfl_xor(sum, 1);
        sum += __shfl_xor(sum, 2);
        sum += __shfl_xor(sum, 4);
        sum += __shfl_xor(sum, 8);
        sum += __shfl_xor(sum, 16);
        float om = e / sum;
        if (l < 32) s_omega[l] = om;
    }
    __syncthreads();

    // G: out[i][d] = sum_k omega[k] * (hi+lo)[sel_k][d] + bias[d]; 2 cols/lane
    {
        int d0 = 2 * l;
        const float2* b2 = (const float2*)bias;
        float2 bb = b2[l];
        float o0 = bb.x;
        float o1 = bb.y;
#pragma unroll
        for (int k = 0; k < TOPK; ++k) {
            float wk = s_omega[k];
            unsigned ph = *(const unsigned*)(&s_xh[k * 136 + d0]);
            unsigned pl = *(const unsigned*)(&s_xl[k * 136 + d0]);
            float x0 = bf2f((unsigned short)(ph & 0xffffu)) +
                       bf2f((unsigned short)(pl & 0xffffu));
            float x1 = bf2f((unsigned short)(ph >> 16)) +
                       bf2f((unsigned short)(pl >> 16));
            o0 = fmaf(wk, x0, o0);
            o1 = fmaf(wk, x1, o1);
        }
        float2 o = make_float2(o0, o1);
        *(float2*)(outp + (size_t)i * 128 + d0) = o;
    }
}

extern "C" void kernel_launch(void* const* d_in, const int* in_sizes, int n_in,
                              void* d_out, int out_size, void* d_ws, size_t ws_size,
                              hipStream_t stream) {
    const float* feat = (const float*)d_in[0];
    const float* ew = (const float*)d_in[1];
    const float* weight = (const float*)d_in[2];
    const float* bias = (const float*)d_in[3];
    const int* nbr = (const int*)d_in[4];
    float* outp = (float*)d_out;
    int n = in_sizes[0] / NNODE_DIN;  // 50000

    unsigned short* xh = (unsigned short*)d_ws;            // n x 128 bf16
    unsigned short* xl = xh + (size_t)n * NNODE_DOUT;      // n x 128 bf16

    int grid1 = (n + 127) / 128;
    hipLaunchKernelGGL(k1_gemm, dim3(grid1), dim3(256), 0, stream, feat, weight, xh, xl, n);
    hipLaunchKernelGGL(k2_conv, dim3(n), dim3(64), 0, stream, ew, nbr, bias, xh, xl, outp, n);
}

// Round 3
// 302.770 us; speedup vs baseline: 7.9143x; 7.9143x over previous
//
#include <hip/hip_runtime.h>
#include <hip/hip_bf16.h>
#include <cstring>

// Problem constants (match reference)
#define NNODE_DIN 128
#define NNODE_DOUT 128
#define DEG 48
#define TOPK 32

typedef __bf16 bf16x8 __attribute__((ext_vector_type(8)));
typedef float floatx4 __attribute__((ext_vector_type(4)));

__device__ inline unsigned short f2bf(float f) {
    __bf16 h = (__bf16)f;
    return __builtin_bit_cast(unsigned short, h);
}
__device__ inline float bf2f(unsigned short u) {
    unsigned v = ((unsigned)u) << 16;
    return __builtin_bit_cast(float, v);
}

// ---------------------------------------------------------------------------
// Kernel 1: x = feat @ weight (fp32 accumulate). Store split-bf16: hi = bf16(x),
// lo = bf16(x - hi). Together ~2^-18 relative precision.
// Block = 256 threads; each thread: 4 rows x 16 cols. 128 rows/block.
// Weight (128x128 fp32 = 64KB) staged in LDS.
// NOTE: all acc[] indices must be compile-time constants after unrolling —
// a runtime-staggered index here previously forced acc into scratch (4 GB of
// spill write-backs, 2.2 ms). The 4-way LDS read conflict this leaves costs
// 1.58x on the LDS pipe, which stays below the FMA issue cost — acceptable.
// ---------------------------------------------------------------------------
__global__ __launch_bounds__(256) void k1_gemm(
    const float* __restrict__ feat, const float* __restrict__ weight,
    unsigned short* __restrict__ xh, unsigned short* __restrict__ xl, int n) {
    __shared__ float s_wt[128 * 128];

    int t = threadIdx.x;
    const float4* wg4 = (const float4*)weight;
    float4* sw4 = (float4*)s_wt;
#pragma unroll
    for (int ii = 0; ii < 16; ++ii) sw4[ii * 256 + t] = wg4[ii * 256 + t];
    __syncthreads();

    int colgrp = t & 7;
    int rowgrp = t >> 3;
    int c0 = colgrp * 16;
    int r0 = blockIdx.x * 128 + rowgrp * 4;

    float acc[4][16];
#pragma unroll
    for (int j = 0; j < 4; ++j)
#pragma unroll
        for (int cidx = 0; cidx < 16; ++cidx) acc[j][cidx] = 0.0f;

    for (int d0 = 0; d0 < 128; d0 += 4) {
        float4 f[4];
#pragma unroll
        for (int j = 0; j < 4; ++j) {
            int r = r0 + j;
            if (r < n) {
                f[j] = *(const float4*)(feat + (size_t)r * 128 + d0);
            } else {
                f[j] = make_float4(0.f, 0.f, 0.f, 0.f);
            }
        }
#pragma unroll
        for (int i = 0; i < 4; ++i) {
            float4 wv[4];
#pragma unroll
            for (int cc = 0; cc < 4; ++cc) {
                wv[cc] = *(const float4*)&s_wt[(d0 + i) * 128 + c0 + cc * 4];
            }
#pragma unroll
            for (int j = 0; j < 4; ++j) {
                float fv = (&f[j].x)[i];
#pragma unroll
                for (int cc = 0; cc < 4; ++cc) {
                    acc[j][cc * 4 + 0] = fmaf(fv, wv[cc].x, acc[j][cc * 4 + 0]);
                    acc[j][cc * 4 + 1] = fmaf(fv, wv[cc].y, acc[j][cc * 4 + 1]);
                    acc[j][cc * 4 + 2] = fmaf(fv, wv[cc].z, acc[j][cc * 4 + 2]);
                    acc[j][cc * 4 + 3] = fmaf(fv, wv[cc].w, acc[j][cc * 4 + 3]);
                }
            }
        }
    }

#pragma unroll
    for (int j = 0; j < 4; ++j) {
        int r = r0 + j;
        if (r < n) {
            unsigned uh[8], ul[8];
#pragma unroll
            for (int p = 0; p < 8; ++p) {
                float a0 = acc[j][2 * p];
                float a1 = acc[j][2 * p + 1];
                unsigned short h0 = f2bf(a0);
                unsigned short h1 = f2bf(a1);
                unsigned short l0 = f2bf(a0 - bf2f(h0));
                unsigned short l1 = f2bf(a1 - bf2f(h1));
                uh[p] = (unsigned)h0 | ((unsigned)h1 << 16);
                ul[p] = (unsigned)l0 | ((unsigned)l1 << 16);
            }
            uint4* dsth = (uint4*)(xh + (size_t)r * 128 + c0);
            dsth[0] = make_uint4(uh[0], uh[1], uh[2], uh[3]);
            dsth[1] = make_uint4(uh[4], uh[5], uh[6], uh[7]);
            uint4* dstl = (uint4*)(xl + (size_t)r * 128 + c0);
            dstl[0] = make_uint4(ul[0], ul[1], ul[2], ul[3]);
            dstl[1] = make_uint4(ul[4], ul[5], ul[6], ul[7]);
        }
    }
}

// ---------------------------------------------------------------------------
// Kernel 2: one wave (64 threads) per node.
//  A) load 49 candidate weights/ids  B) exact top-32 by (value desc, idx asc)
//  C) gather 32 x-rows (split bf16 hi/lo) into LDS
//  D) 32x32 Gram via split MFMA: G = HH^T + HL^T + LH^T (48 MFMAs)
//  E) weighted-medoid distances  F) softmax * tw / sum  G) aggregate + bias
// ---------------------------------------------------------------------------
__global__ __launch_bounds__(64) void k2_conv(
    const float* __restrict__ ew, const int* __restrict__ nbr,
    const float* __restrict__ bias, const unsigned short* __restrict__ xh,
    const unsigned short* __restrict__ xl, float* __restrict__ outp, int n) {
    __shared__ float s_w[52];
    __shared__ int s_nb[52];
    __shared__ float s_tw[32];
    __shared__ int s_id[32];
    __shared__ unsigned short s_xh[32 * 136];  // 32 rows x 128 bf16, pad to 136
    __shared__ unsigned short s_xl[32 * 136];
    __shared__ float s_diag[32];
    __shared__ float s_dist[32];
    __shared__ float s_omega[32];

    int i = blockIdx.x;
    int l = threadIdx.x;

    // A: candidates = 48 neighbors + self loop (weight 1.0)
    if (l < DEG) {
        s_w[l] = ew[(size_t)i * DEG + l];
        s_nb[l] = nbr[(size_t)i * DEG + l];
    }
    if (l == DEG) {
        s_w[DEG] = 1.0f;
        s_nb[DEG] = i;
    }
    __syncthreads();

    // B: rank-based top-k (exact jax.lax.top_k tie semantics); rank == slot
    if (l < DEG + 1) {
        float wj = s_w[l];
        int rank = 0;
        for (int t2 = 0; t2 < DEG + 1; ++t2) {
            float wt = s_w[t2];
            rank += (wt > wj) || ((wt == wj) && (t2 < l)) ? 1 : 0;
        }
        if (rank < TOPK) {
            s_tw[rank] = wj;
            s_id[rank] = s_nb[l];
        }
    }
    __syncthreads();

    // C: gather 32 rows (hi+lo, 256B each) into LDS; 4 rows per iteration
    {
        int chunk = l & 15;   // 16B chunk within row
        int ksub = l >> 4;    // which of 4 rows this iteration
#pragma unroll
        for (int it = 0; it < 8; ++it) {
            int k = it * 4 + ksub;
            size_t base = (size_t)s_id[k] * 128;
            const uint4* srch = (const uint4*)(xh + base) + chunk;
            const uint4* srcl = (const uint4*)(xl + base) + chunk;
            *(uint4*)(&s_xh[k * 136 + chunk * 8]) = *srch;
            *(uint4*)(&s_xl[k * 136 + chunk * 8]) = *srcl;
        }
    }
    __syncthreads();

    // D: Gram = X*X^T with X ~= H + L:  G = HH^T + HL^T + LH^T (LL^T ~2^-18, dropped)
    int m = l & 15;
    int q = l >> 4;
    floatx4 acc[2][2];
#pragma unroll
    for (int a = 0; a < 2; ++a)
#pragma unroll
        for (int b = 0; b < 2; ++b) acc[a][b] = (floatx4){0.f, 0.f, 0.f, 0.f};

    const __bf16* xbh = (const __bf16*)s_xh;
    const __bf16* xbl = (const __bf16*)s_xl;
#pragma unroll
    for (int kt = 0; kt < 4; ++kt) {
        bf16x8 h0 = *(const bf16x8*)(xbh + m * 136 + kt * 32 + q * 8);
        bf16x8 h1 = *(const bf16x8*)(xbh + (16 + m) * 136 + kt * 32 + q * 8);
        bf16x8 l0 = *(const bf16x8*)(xbl + m * 136 + kt * 32 + q * 8);
        bf16x8 l1 = *(const bf16x8*)(xbl + (16 + m) * 136 + kt * 32 + q * 8);
        acc[0][0] = __builtin_amdgcn_mfma_f32_16x16x32_bf16(h0, h0, acc[0][0], 0, 0, 0);
        acc[0][0] = __builtin_amdgcn_mfma_f32_16x16x32_bf16(h0, l0, acc[0][0], 0, 0, 0);
        acc[0][0] = __builtin_amdgcn_mfma_f32_16x16x32_bf16(l0, h0, acc[0][0], 0, 0, 0);
        acc[0][1] = __builtin_amdgcn_mfma_f32_16x16x32_bf16(h0, h1, acc[0][1], 0, 0, 0);
        acc[0][1] = __builtin_amdgcn_mfma_f32_16x16x32_bf16(h0, l1, acc[0][1], 0, 0, 0);
        acc[0][1] = __builtin_amdgcn_mfma_f32_16x16x32_bf16(l0, h1, acc[0][1], 0, 0, 0);
        acc[1][0] = __builtin_amdgcn_mfma_f32_16x16x32_bf16(h1, h0, acc[1][0], 0, 0, 0);
        acc[1][0] = __builtin_amdgcn_mfma_f32_16x16x32_bf16(h1, l0, acc[1][0], 0, 0, 0);
        acc[1][0] = __builtin_amdgcn_mfma_f32_16x16x32_bf16(l1, h0, acc[1][0], 0, 0, 0);
        acc[1][1] = __builtin_amdgcn_mfma_f32_16x16x32_bf16(h1, h1, acc[1][1], 0, 0, 0);
        acc[1][1] = __builtin_amdgcn_mfma_f32_16x16x32_bf16(h1, l1, acc[1][1], 0, 0, 0);
        acc[1][1] = __builtin_amdgcn_mfma_f32_16x16x32_bf16(l1, h1, acc[1][1], 0, 0, 0);
    }

    // D2: extract diagonal (sq) from Gram so that d2_aa == 0 exactly
    if (q == (m >> 2)) {
        int rd = m & 3;
        s_diag[m] = acc[0][0][rd];
        s_diag[16 + m] = acc[1][1][rd];
    }
    __syncthreads();

    // E: dist[a] = sum_b tw[b] * sqrt(d2 masked by d2>0)
#pragma unroll
    for (int ma = 0; ma < 2; ++ma) {
#pragma unroll
        for (int r = 0; r < 4; ++r) {
            int a = ma * 16 + q * 4 + r;
            float da = s_diag[a];
            float g0 = acc[ma][0][r];
            float g1 = acc[ma][1][r];
            int b0 = m;
            int b1 = 16 + m;
            float d20 = da + s_diag[b0] - 2.0f * g0;
            float d21 = da + s_diag[b1] - 2.0f * g1;
            float t0 = (d20 > 0.0f) ? sqrtf(d20) : 0.0f;
            float t1 = (d21 > 0.0f) ? sqrtf(d21) : 0.0f;
            float v = s_tw[b0] * t0 + s_tw[b1] * t1;
            v += __shfl_xor(v, 1);
            v += __shfl_xor(v, 2);
            v += __shfl_xor(v, 4);
            v += __shfl_xor(v, 8);
            if (m == 0) s_dist[a] = v;
        }
    }
    __syncthreads();

    // F: omega = exp(-dist - max(-dist)) * tw, normalized
    {
        int k32 = l & 31;
        float s = s_dist[k32];
        float mn = s;
        mn = fminf(mn, __shfl_xor(mn, 1));
        mn = fminf(mn, __shfl_xor(mn, 2));
        mn = fminf(mn, __shfl_xor(mn, 4));
        mn = fminf(mn, __shfl_xor(mn, 8));
        mn = fminf(mn, __shfl_xor(mn, 16));
        float e = expf(mn - s) * s_tw[k32];
        float sum = e;
        sum += __shfl_xor(sum, 1);
        sum += __shfl_xor(sum, 2);
        sum += __shfl_xor(sum, 4);
        sum += __shfl_xor(sum, 8);
        sum += __shfl_xor(sum, 16);
        float om = e / sum;
        if (l < 32) s_omega[l] = om;
    }
    __syncthreads();

    // G: out[i][d] = sum_k omega[k] * (hi+lo)[sel_k][d] + bias[d]; 2 cols/lane
    {
        int d0 = 2 * l;
        const float2* b2 = (const float2*)bias;
        float2 bb = b2[l];
        float o0 = bb.x;
        float o1 = bb.y;
#pragma unroll
        for (int k = 0; k < TOPK; ++k) {
            float wk = s_omega[k];
            unsigned ph = *(const unsigned*)(&s_xh[k * 136 + d0]);
            unsigned pl = *(const unsigned*)(&s_xl[k * 136 + d0]);
            float x0 = bf2f((unsigned short)(ph & 0xffffu)) +
                       bf2f((unsigned short)(pl & 0xffffu));
            float x1 = bf2f((unsigned short)(ph >> 16)) +
                       bf2f((unsigned short)(pl >> 16));
            o0 = fmaf(wk, x0, o0);
            o1 = fmaf(wk, x1, o1);
        }
        float2 o = make_float2(o0, o1);
        *(float2*)(outp + (size_t)i * 128 + d0) = o;
    }
}

extern "C" void kernel_launch(void* const* d_in, const int* in_sizes, int n_in,
                              void* d_out, int out_size, void* d_ws, size_t ws_size,
                              hipStream_t stream) {
    const float* feat = (const float*)d_in[0];
    const float* ew = (const float*)d_in[1];
    const float* weight = (const float*)d_in[2];
    const float* bias = (const float*)d_in[3];
    const int* nbr = (const int*)d_in[4];
    float* outp = (float*)d_out;
    int n = in_sizes[0] / NNODE_DIN;  // 50000

    unsigned short* xh = (unsigned short*)d_ws;            // n x 128 bf16
    unsigned short* xl = xh + (size_t)n * NNODE_DOUT;      // n x 128 bf16

    int grid1 = (n + 127) / 128;
    hipLaunchKernelGGL(k1_gemm, dim3(grid1), dim3(256), 0, stream, feat, weight, xh, xl, n);
    hipLaunchKernelGGL(k2_conv, dim3(n), dim3(64), 0, stream, ew, nbr, bias, xh, xl, outp, n);
}